// Round 6
// baseline (112.321 us; speedup 1.0000x reference)
//
#include <hip/hip_runtime.h>
#include <math.h>

#define EPS_F 1e-6f
#define S_DIM 768
#define W_DIM 32
#define H_DIM 12
#define NK 33   // intervals = W_DIM + 1

// Single fused kernel: per-block PWL table build (cheap, hidden under the
// row's global-load latency) + wave-per-row PWL evaluation.
//
// out(dist) = b_out[h] + sum_w relu(dist*w1[w]+b_in[w])*W_out[h,w] is
// piecewise-linear in dist with 32 h-independent hinges t_w = -b_in/w1.
// Interval k (= #{hinges < dist}) selects per-h coefficients (A_k, B_k).

__global__ __launch_bounds__(256) void cope_fire_kernel(
    const float* __restrict__ attn,   // (H*S, S)
    const float* __restrict__ W_in,   // (32,1)
    const float* __restrict__ b_in,   // (32,)
    const float* __restrict__ W_out,  // (H,32)
    const float* __restrict__ b_out,  // (H,)
    const float* __restrict__ c_p,
    const float* __restrict__ Lm_p,
    const float* __restrict__ iL_p,
    float* __restrict__ out)
{
    const int t    = threadIdx.x;
    const int lane = t & 63;
    const int wave = t >> 6;
    const int row  = blockIdx.x * 4 + wave;       // one wave per row
    const int h    = blockIdx.x / (S_DIM / 4);    // block-uniform

    __shared__ float  s_w1[W_DIM], s_bin[W_DIM], s_wout[W_DIM];
    __shared__ float  s_th[W_DIM];
    __shared__ int    s_rk[W_DIM];
    __shared__ float  sh[1 + W_DIM];   // sh[0] = -inf sentinel; sh[1..32] sorted hinges
    __shared__ float2 sAB[NK];

    // ---- issue the row's global loads FIRST (latency overlaps table build) ----
    const float* rowp = attn + (size_t)row * S_DIM + lane * 12;
    float4 v0 = *(const float4*)(rowp);
    float4 v1 = *(const float4*)(rowp + 4);
    float4 v2 = *(const float4*)(rowp + 8);

    const float c   = c_p[0];                      // uniform scalar loads
    const float thr = fabsf(Lm_p[0] * iL_p[0]);
    const float bo  = b_out[h];

    // ---- stage weights + hinges ----
    if (t < W_DIM) {
        float w1 = W_in[t];
        float bv = b_in[t];
        s_w1[t]   = w1;
        s_bin[t]  = bv;
        s_wout[t] = W_out[h * W_DIM + t];
        s_th[t]   = (w1 != 0.0f) ? (-bv / w1) : __builtin_inff();
    }
    if (t == 64) sh[0] = -__builtin_inff();
    __syncthreads();

    // ---- rank-sort hinges (wave 0, broadcast LDS reads) ----
    if (t < W_DIM) {
        float mine = s_th[t];
        int r = 0;
        for (int v = 0; v < W_DIM; v++) {
            float o = s_th[v];
            if (o < mine || (o == mine && v < t)) r++;
        }
        s_rk[t] = r;
        sh[1 + r] = mine;
    }
    __syncthreads();

    // ---- per-(h,k) PWL coefficients (threads 0..32, broadcast LDS reads) ----
    if (t < NK) {
        float A = 0.0f, B = bo;
        for (int w = 0; w < W_DIM; w++) {
            float w1 = s_w1[w], bv = s_bin[w], ov = s_wout[w];
            int   r  = s_rk[w];
            bool active = (w1 > 0.0f) ? (t > r)
                        : (w1 < 0.0f) ? (t <= r)
                        : (bv > 0.0f);
            if (active) { A = fmaf(w1, ov, A); B = fmaf(bv, ov, B); }
        }
        sAB[t] = make_float2(A, B);
    }

    // ---- sigmoid on the 12 loaded elements (loads have landed by now) ----
    float g[12] = { v0.x, v0.y, v0.z, v0.w, v1.x, v1.y, v1.z, v1.w,
                    v2.x, v2.y, v2.z, v2.w };
#pragma unroll
    for (int i = 0; i < 12; i++)
        g[i] = __builtin_amdgcn_rcpf(1.0f + __expf(-g[i]));

    // ---- lane total + inclusive wave scan of lane totals ----
    float T0 = 0.0f;
#pragma unroll
    for (int i = 0; i < 12; i++) T0 += g[i];
    float P = T0;
#pragma unroll
    for (int d = 1; d < 64; d <<= 1) {
        float y = __shfl_up(P, d, 64);
        if (lane >= d) P += y;
    }
    const float total = __shfl(P, 63, 64);
    const float base  = total - P + T0;   // suffix sum at lane's first element

    const float den     = __logf(fabsf(c * fminf(total, thr)) + 1.0f) + EPS_F;
    const float inv_den = __builtin_amdgcn_rcpf(den);

    // dist for all 12 elements (strictly decreasing over i)
    float e = 0.0f;
#pragma unroll
    for (int i = 0; i < 12; i++) {
        float pos = base - e;
        e += g[i];
        g[i] = __logf(fabsf(c * pos) + 1.0f) * inv_den;
    }

    __syncthreads();   // tables ready

    // preload search-tree levels 16/8/4 once (VGPR-resident, reused x12)
    const float u16 = sh[16];
    const float u8a = sh[8],  u8b = sh[24];
    const float u4a = sh[4],  u4b = sh[12], u4c = sh[20], u4d = sh[28];

    // ---- independent per-element binary search + PWL eval (12-way ILP) ----
    float o[12];
#pragma unroll
    for (int i = 0; i < 12; i++) {
        float d = g[i];
        int k = 0;
        if (u16 < d) k = 16;
        float l2 = (k != 0) ? u8b : u8a;          // sh[k+8]
        if (l2 < d) k += 8;
        float l3ab = (k & 8) ? u4b : u4a;
        float l3cd = (k & 8) ? u4d : u4c;
        float l3   = (k & 16) ? l3cd : l3ab;      // sh[k+4]
        if (l3 < d) k += 4;
        if (sh[k + 2] < d) k += 2;
        if (sh[k + 1] < d) k += 1;
        if (sh[k + 1] < d) k += 1;                // fixup -> k in [0,32]
        float2 ab = sAB[k];
        o[i] = fmaf(d, ab.x, ab.y);
    }

    float* op = out + (size_t)row * S_DIM + lane * 12;
    *(float4*)(op)     = make_float4(o[0], o[1], o[2],  o[3]);
    *(float4*)(op + 4) = make_float4(o[4], o[5], o[6],  o[7]);
    *(float4*)(op + 8) = make_float4(o[8], o[9], o[10], o[11]);
}

extern "C" void kernel_launch(void* const* d_in, const int* in_sizes, int n_in,
                              void* d_out, int out_size, void* d_ws, size_t ws_size,
                              hipStream_t stream) {
    const float* attn  = (const float*)d_in[0];
    const float* W_in  = (const float*)d_in[1];
    const float* b_in  = (const float*)d_in[2];
    const float* W_out = (const float*)d_in[3];
    const float* b_out = (const float*)d_in[4];
    const float* c_p   = (const float*)d_in[5];
    const float* Lm_p  = (const float*)d_in[6];
    const float* iL_p  = (const float*)d_in[7];
    float* out = (float*)d_out;

    const int rows = H_DIM * S_DIM;            // 9216 rows, one wave each
    cope_fire_kernel<<<rows / 4, 256, 0, stream>>>(
        attn, W_in, b_in, W_out, b_out, c_p, Lm_p, iL_p, out);
}

// Round 7
// 107.550 us; speedup vs baseline: 1.0444x; 1.0444x over previous
//
#include <hip/hip_runtime.h>
#include <math.h>

#define EPS_F 1e-6f
#define S_DIM 768
#define W_DIM 32
#define H_DIM 12
#define NK 33           // intervals = W_DIM + 1
#define RPB 8           // rows per block (2 per wave)
#define LN2 0.69314718f
#define LOG2E 1.44269504f

// Single fused kernel, 8 rows/block: per-block PWL table build amortized over
// 8 rows; each wave processes 2 rows with both rows' loads issued up front.
//
// out(dist) = b_out[h] + sum_w relu(dist*w1[w]+b_in[w])*W_out[h,w] is
// piecewise-linear in dist with 32 h-independent hinges t_w = -b_in/w1.
// Interval k (= #{hinges < dist}) selects per-h coefficients (A_k, B_k).

__global__ __launch_bounds__(256) void cope_fire_kernel(
    const float* __restrict__ attn,   // (H*S, S)
    const float* __restrict__ W_in,   // (32,1)
    const float* __restrict__ b_in,   // (32,)
    const float* __restrict__ W_out,  // (H,32)
    const float* __restrict__ b_out,  // (H,)
    const float* __restrict__ c_p,
    const float* __restrict__ Lm_p,
    const float* __restrict__ iL_p,
    float* __restrict__ out)
{
    const int t    = threadIdx.x;
    const int lane = t & 63;
    const int wave = t >> 6;
    const int row0 = blockIdx.x * RPB + wave;     // wave's first row
    const int row1 = row0 + 4;                    // wave's second row
    const int h    = blockIdx.x / (S_DIM / RPB);  // 96 blocks per h (uniform)

    __shared__ float  s_w1[W_DIM], s_bin[W_DIM], s_wout[W_DIM];
    __shared__ float  s_th[W_DIM];
    __shared__ int    s_rk[W_DIM];
    __shared__ float  sh[1 + W_DIM];   // sh[0] = -inf; sh[1..32] sorted hinges
    __shared__ float2 sAB[NK];

    // ---- issue BOTH rows' global loads first (max MLP per wave) ----
    const float* r0p = attn + (size_t)row0 * S_DIM + lane * 12;
    const float* r1p = attn + (size_t)row1 * S_DIM + lane * 12;
    float4 a0 = *(const float4*)(r0p);
    float4 a1 = *(const float4*)(r0p + 4);
    float4 a2 = *(const float4*)(r0p + 8);
    float4 c0 = *(const float4*)(r1p);
    float4 c1 = *(const float4*)(r1p + 4);
    float4 c2 = *(const float4*)(r1p + 8);

    const float c   = c_p[0];                     // uniform scalar loads
    const float thr = fabsf(Lm_p[0] * iL_p[0]);
    const float bo  = b_out[h];

    // ---- stage weights + hinges ----
    if (t < W_DIM) {
        float w1 = W_in[t];
        float bv = b_in[t];
        s_w1[t]   = w1;
        s_bin[t]  = bv;
        s_wout[t] = W_out[h * W_DIM + t];
        s_th[t]   = (w1 != 0.0f) ? (-bv / w1) : __builtin_inff();
    }
    if (t == 64) sh[0] = -__builtin_inff();
    __syncthreads();

    // ---- rank-sort hinges (wave 0, broadcast LDS reads) ----
    if (t < W_DIM) {
        float mine = s_th[t];
        int r = 0;
        for (int v = 0; v < W_DIM; v++) {
            float o = s_th[v];
            if (o < mine || (o == mine && v < t)) r++;
        }
        s_rk[t] = r;
        sh[1 + r] = mine;
    }
    __syncthreads();

    // ---- per-(h,k) PWL coefficients (threads 0..32) ----
    if (t < NK) {
        float A = 0.0f, B = bo;
        for (int w = 0; w < W_DIM; w++) {
            float w1 = s_w1[w], bv = s_bin[w], ov = s_wout[w];
            int   r  = s_rk[w];
            bool active = (w1 > 0.0f) ? (t > r)
                        : (w1 < 0.0f) ? (t <= r)
                        : (bv > 0.0f);
            if (active) { A = fmaf(w1, ov, A); B = fmaf(bv, ov, B); }
        }
        sAB[t] = make_float2(A, B);
    }

    // ---- sigmoid, both rows (2x12 independent ops) ----
    float g[2][12] = { { a0.x, a0.y, a0.z, a0.w, a1.x, a1.y, a1.z, a1.w,
                         a2.x, a2.y, a2.z, a2.w },
                       { c0.x, c0.y, c0.z, c0.w, c1.x, c1.y, c1.z, c1.w,
                         c2.x, c2.y, c2.z, c2.w } };
#pragma unroll
    for (int r = 0; r < 2; r++)
#pragma unroll
        for (int i = 0; i < 12; i++)
            g[r][i] = __builtin_amdgcn_rcpf(1.0f + exp2f(g[r][i] * -LOG2E));

    // ---- lane totals + two independent inclusive wave scans ----
    float T[2] = { 0.0f, 0.0f };
#pragma unroll
    for (int r = 0; r < 2; r++)
#pragma unroll
        for (int i = 0; i < 12; i++) T[r] += g[r][i];
    float P0 = T[0], P1 = T[1];
#pragma unroll
    for (int d = 1; d < 64; d <<= 1) {
        float y0 = __shfl_up(P0, d, 64);
        float y1 = __shfl_up(P1, d, 64);
        if (lane >= d) { P0 += y0; P1 += y1; }
    }
    const float tot0 = __shfl(P0, 63, 64);
    const float tot1 = __shfl(P1, 63, 64);
    const float base0 = tot0 - P0 + T[0];   // suffix sum at lane's first elem
    const float base1 = tot1 - P1 + T[1];

    // log2-space: dist = log2(|c*pos|+1) * (ln2 * inv_den)
    const float id0 = LN2 * __builtin_amdgcn_rcpf(
        fmaf(LN2, __log2f(fabsf(c * fminf(tot0, thr)) + 1.0f), EPS_F));
    const float id1 = LN2 * __builtin_amdgcn_rcpf(
        fmaf(LN2, __log2f(fabsf(c * fminf(tot1, thr)) + 1.0f), EPS_F));

    // ---- dist for all elements, both rows ----
    float e0 = 0.0f, e1 = 0.0f;
#pragma unroll
    for (int i = 0; i < 12; i++) {
        float p0 = base0 - e0; e0 += g[0][i];
        float p1 = base1 - e1; e1 += g[1][i];
        g[0][i] = __log2f(fabsf(c * p0) + 1.0f) * id0;
        g[1][i] = __log2f(fabsf(c * p1) + 1.0f) * id1;
    }

    __syncthreads();   // tables ready

    // preload search-tree levels 16/8/4 once (VGPR-resident, reused x24)
    const float u16 = sh[16];
    const float u8a = sh[8],  u8b = sh[24];
    const float u4a = sh[4],  u4b = sh[12], u4c = sh[20], u4d = sh[28];

    // ---- independent per-element binary search + PWL eval (24-way ILP) ----
    float o[2][12];
#pragma unroll
    for (int r = 0; r < 2; r++) {
#pragma unroll
        for (int i = 0; i < 12; i++) {
            float d = g[r][i];
            int k = 0;
            if (u16 < d) k = 16;
            float l2 = (k != 0) ? u8b : u8a;          // sh[k+8]
            if (l2 < d) k += 8;
            float l3ab = (k & 8) ? u4b : u4a;
            float l3cd = (k & 8) ? u4d : u4c;
            float l3   = (k & 16) ? l3cd : l3ab;      // sh[k+4]
            if (l3 < d) k += 4;
            if (sh[k + 2] < d) k += 2;
            if (sh[k + 1] < d) k += 1;
            if (sh[k + 1] < d) k += 1;                // fixup -> k in [0,32]
            float2 ab = sAB[k];
            o[r][i] = fmaf(d, ab.x, ab.y);
        }
    }

    float* o0 = out + (size_t)row0 * S_DIM + lane * 12;
    float* o1 = out + (size_t)row1 * S_DIM + lane * 12;
    *(float4*)(o0)     = make_float4(o[0][0], o[0][1], o[0][2],  o[0][3]);
    *(float4*)(o0 + 4) = make_float4(o[0][4], o[0][5], o[0][6],  o[0][7]);
    *(float4*)(o0 + 8) = make_float4(o[0][8], o[0][9], o[0][10], o[0][11]);
    *(float4*)(o1)     = make_float4(o[1][0], o[1][1], o[1][2],  o[1][3]);
    *(float4*)(o1 + 4) = make_float4(o[1][4], o[1][5], o[1][6],  o[1][7]);
    *(float4*)(o1 + 8) = make_float4(o[1][8], o[1][9], o[1][10], o[1][11]);
}

extern "C" void kernel_launch(void* const* d_in, const int* in_sizes, int n_in,
                              void* d_out, int out_size, void* d_ws, size_t ws_size,
                              hipStream_t stream) {
    const float* attn  = (const float*)d_in[0];
    const float* W_in  = (const float*)d_in[1];
    const float* b_in  = (const float*)d_in[2];
    const float* W_out = (const float*)d_in[3];
    const float* b_out = (const float*)d_in[4];
    const float* c_p   = (const float*)d_in[5];
    const float* Lm_p  = (const float*)d_in[6];
    const float* iL_p  = (const float*)d_in[7];
    float* out = (float*)d_out;

    const int blocks = H_DIM * S_DIM / RPB;        // 1152 blocks, 8 rows each
    cope_fire_kernel<<<blocks, 256, 0, stream>>>(
        attn, W_in, b_in, W_out, b_out, c_p, Lm_p, iL_p, out);
}

// Round 8
// 104.472 us; speedup vs baseline: 1.0751x; 1.0295x over previous
//
#include <hip/hip_runtime.h>
#include <math.h>

#define EPS_F 1e-6f
#define S_DIM 768
#define W_DIM 32
#define H_DIM 12
#define NK 33   // intervals = W_DIM + 1

// ws float layout:
//   [0 .. 32)                      sorted hinge values (ascending)
//   [32 + h*2*NK + 2k]  = A_k(h)   (slope)
//   [32 + h*2*NK + 2k+1]= B_k(h)   (intercept, includes b_out[h])

// ---------------- setup: build sorted hinges + per-(h,k) PWL tables ----------
__global__ __launch_bounds__(512) void cope_setup_kernel(
    const float* __restrict__ W_in, const float* __restrict__ b_in,
    const float* __restrict__ W_out, const float* __restrict__ b_out,
    float* __restrict__ ws)
{
    __shared__ float th[W_DIM];
    __shared__ int   rk[W_DIM];
    const int t = threadIdx.x;

    if (t < W_DIM) {
        float w1 = W_in[t], b = b_in[t];
        th[t] = (w1 != 0.0f) ? (-b / w1) : __builtin_inff();
    }
    __syncthreads();

    if (t < W_DIM) {
        float mine = th[t];
        int r = 0;
        for (int v = 0; v < W_DIM; v++) {
            float o = th[v];
            if (o < mine || (o == mine && v < t)) r++;
        }
        rk[t] = r;          // sorted rank of hinge t (ties broken by index)
        ws[r] = mine;       // sorted hinge array
    }
    __syncthreads();

    if (t < H_DIM * NK) {
        int h = t / NK, k = t % NK;   // interval k: exactly k hinges < dist
        float A = 0.0f, B = b_out[h];
        for (int w = 0; w < W_DIM; w++) {
            float w1 = W_in[w], bv = b_in[w], ov = W_out[h * W_DIM + w];
            bool active = (w1 > 0.0f) ? (k > rk[w])
                        : (w1 < 0.0f) ? (k <= rk[w])
                        : (bv > 0.0f);
            if (active) { A += w1 * ov; B += bv * ov; }
        }
        ws[W_DIM + h * 2 * NK + 2 * k]     = A;
        ws[W_DIM + h * 2 * NK + 2 * k + 1] = B;
    }
}

// ---------------- main: wave-per-row, shallow-LDS PWL evaluation ------------
__global__ __launch_bounds__(256) void cope_fire_kernel(
    const float* __restrict__ attn,   // (H*S, S)
    const float* __restrict__ c_p,
    const float* __restrict__ Lm_p,
    const float* __restrict__ iL_p,
    const float* __restrict__ ws,
    float* __restrict__ out)
{
    const int t    = threadIdx.x;
    const int lane = t & 63;
    const int wave = t >> 6;
    const int row  = blockIdx.x * 4 + wave;       // one wave per row
    const int h    = blockIdx.x / (S_DIM / 4);    // block-uniform

    __shared__ float  sh1[W_DIM];   // sorted hinges, 16B-aligned groups of 4
    __shared__ float2 sAB[NK];

    if (t < W_DIM) sh1[t] = ws[t];
    if (t < NK) {
        const float* p = ws + W_DIM + h * 2 * NK + 2 * t;
        sAB[t] = make_float2(p[0], p[1]);
    }

    // SGPR-resident tree comparators (uniform constant-index loads)
    const float h15 = ws[15];
    const float h7  = ws[7],  h23 = ws[23];
    const float h3  = ws[3],  h11 = ws[11], h19 = ws[19], h27 = ws[27];
    const float c   = c_p[0];
    const float thr = fabsf(Lm_p[0] * iL_p[0]);

    // load 12 contiguous elements per lane; sigmoid
    const float* rowp = attn + (size_t)row * S_DIM + lane * 12;
    float4 v0 = *(const float4*)(rowp);
    float4 v1 = *(const float4*)(rowp + 4);
    float4 v2 = *(const float4*)(rowp + 8);
    float g[12] = { v0.x, v0.y, v0.z, v0.w, v1.x, v1.y, v1.z, v1.w,
                    v2.x, v2.y, v2.z, v2.w };
#pragma unroll
    for (int i = 0; i < 12; i++)
        g[i] = __builtin_amdgcn_rcpf(1.0f + __expf(-g[i]));

    // lane total + inclusive wave scan of lane totals
    float T0 = 0.0f;
#pragma unroll
    for (int i = 0; i < 12; i++) T0 += g[i];
    float P = T0;
#pragma unroll
    for (int d = 1; d < 64; d <<= 1) {
        float y = __shfl_up(P, d, 64);
        if (lane >= d) P += y;
    }
    const float total = __shfl(P, 63, 64);
    const float base_s = total - P + T0;  // suffix sum at lane's first element

    const float den     = __logf(fabsf(c * fminf(total, thr)) + 1.0f) + EPS_F;
    const float inv_den = __builtin_amdgcn_rcpf(den);

    // dist for all 12 elements (in-place over g)
    float e = 0.0f;
#pragma unroll
    for (int i = 0; i < 12; i++) {
        float pos = base_s - e;
        e += g[i];
        g[i] = __logf(fabsf(c * pos) + 1.0f) * inv_den;
    }

    __syncthreads();   // tables ready

    // ---- per-element search: 3 SGPR-tree levels -> 1x ds_read_b128 + count ----
    // base = (k & ~3) from three uniform compares; then
    // k = base + #{sh1[base+j] < d, j=0..3}; finally one sAB[k] read.
    float o[12];
#pragma unroll
    for (int i = 0; i < 12; i++) {
        float d = g[i];
        bool m1 = (h15 < d);
        float l2 = m1 ? h23 : h7;
        bool m2 = (l2 < d);
        float l3 = m2 ? (m1 ? h27 : h11) : (m1 ? h19 : h3);
        bool m3 = (l3 < d);
        int base = (m1 ? 16 : 0) + (m2 ? 8 : 0) + (m3 ? 4 : 0);

        float4 hv = *(const float4*)(&sh1[base]);   // 16B-aligned LDS read
        int k = base + (hv.x < d) + (hv.y < d) + (hv.z < d) + (hv.w < d);

        float2 ab = sAB[k];
        o[i] = fmaf(d, ab.x, ab.y);
    }

    float* op = out + (size_t)row * S_DIM + lane * 12;
    *(float4*)(op)     = make_float4(o[0], o[1], o[2],  o[3]);
    *(float4*)(op + 4) = make_float4(o[4], o[5], o[6],  o[7]);
    *(float4*)(op + 8) = make_float4(o[8], o[9], o[10], o[11]);
}

extern "C" void kernel_launch(void* const* d_in, const int* in_sizes, int n_in,
                              void* d_out, int out_size, void* d_ws, size_t ws_size,
                              hipStream_t stream) {
    const float* attn  = (const float*)d_in[0];
    const float* W_in  = (const float*)d_in[1];
    const float* b_in  = (const float*)d_in[2];
    const float* W_out = (const float*)d_in[3];
    const float* b_out = (const float*)d_in[4];
    const float* c_p   = (const float*)d_in[5];
    const float* Lm_p  = (const float*)d_in[6];
    const float* iL_p  = (const float*)d_in[7];
    float* out = (float*)d_out;
    float* ws  = (float*)d_ws;

    cope_setup_kernel<<<1, 512, 0, stream>>>(W_in, b_in, W_out, b_out, ws);

    const int rows = H_DIM * S_DIM;            // 9216 rows, one wave each
    cope_fire_kernel<<<rows / 4, 256, 0, stream>>>(
        attn, c_p, Lm_p, iL_p, ws, out);
}